// Round 6
// baseline (479.842 us; speedup 1.0000x reference)
//
#include <hip/hip_runtime.h>

// Forward-fill (LOCF) along L for x:(B,L,N) fp32, NaN = missing.
// Outputs: x_filled (B*L*N fp32) then mask as 0.0/1.0 fp32, concatenated.
//
// R10 (this round): prefix+patch (single x read, NT stores) with the x read
// staged via global_load_lds DMA (batches of 8 rows per wave, counted vmcnt).
// Rationale: 6 rounds show NT versions stuck at 428-455 us independent of
// bytes (402 vs 536 MB), stream count, staging depth, kernel count -> the
// read-return path (not bytes in flight) is the suspected cap. DMA-to-LDS
// returns to LDS instead of VGPRs -- the one untested path (m97's GEMM
// sustains multi-TB/s through it).
//   - counted waits: vmcnt(16) leaves the previous batch's 16 NT stores in
//     flight (never drain stores); vmcnt(0) only for batch 0.
//   - vmcnt retires oldest-first (m135), so vmcnt(16) == "8 DMAs of this
//     batch done" when 16 stores were issued after them.
//   - LDS slot WAR: lgkmcnt(0) + sched_barrier before re-issuing DMA.
//   - LC=32 -> 1024 blocks = 4 blocks/CU (32 KB LDS each), 16 waves/CU.
//
// R9 lesson: fewer/longer streams (LC=64, 2 blocks/CU) neutral-to-worse: 455.
// R8 lesson: single-read + cached stores = 542; NT >> cached for the write
//   streams (every NT version 428-455, every cached version 542-600).
// R7 lesson: agent-scope acquire/release in a streaming kernel = L2
//   cache-maintenance storm (VALUBusy 2.5%, HBM 14%). Never again.
//   Also: bench dur ~= 2x sum of kernel dispatch times (k_fused 300 -> 599.7).
// R6 lesson: register-staging loads (4x MLP) neutral.
// R3 lesson: nt LOADS on x prevented L3 allocation (+40 us) - x loads cached.
// R2 lesson: __builtin_nontemporal_* requires clang ext_vector_type.

typedef float floatx4 __attribute__((ext_vector_type(4)));

constexpr int B = 32, L = 4096, N = 256;
constexpr int N4 = N / 4;   // 64 float4 lanes across channels == one wave
constexpr int CPB = 4;      // chunks (waves) per 256-thread block

__device__ __forceinline__ float dev_nan() { return __int_as_float(0x7fc00000); }
__device__ __forceinline__ floatx4 nan4() {
    return floatx4{dev_nan(), dev_nan(), dev_nan(), dev_nan()};
}

// last[c] = v[c] if v[c] observed (non-NaN) else last[c]   (v is NEWER)
__device__ __forceinline__ void upd(floatx4& last, const floatx4 v) {
    last.x = (v.x == v.x) ? v.x : last.x;
    last.y = (v.y == v.y) ? v.y : last.y;
    last.z = (v.z == v.z) ? v.z : last.z;
    last.w = (v.w == v.w) ? v.w : last.w;
}

// 16B-per-lane async global->LDS DMA. LDS dest must be the WAVE-UNIFORM
// slot base (hardware adds lane*16); global src is per-lane (m173).
__device__ __forceinline__ void lds_dma16(const floatx4* g, floatx4* l) {
    __builtin_amdgcn_global_load_lds(
        (__attribute__((address_space(1))) void*)(floatx4*)g,
        (__attribute__((address_space(3))) void*)l, 16, 0, 0);
}

// ---------------- Pass 1 (DMA-staged): prefix fill + tail + first-obs ----
constexpr int LCD = 32;     // rows per chunk
constexpr int SD  = 8;      // rows per DMA batch

template <bool HASMASK>
__global__ __launch_bounds__(256) void k_prefix_dma(const floatx4* __restrict__ x4,
                                                    floatx4* __restrict__ out4,
                                                    floatx4* __restrict__ m4,
                                                    floatx4* __restrict__ tail4,
                                                    unsigned int* __restrict__ fo) {
    constexpr int LC = LCD, C = L / LC;
    __shared__ floatx4 st[CPB][SD][N4];          // 32 KB / block
    const int gid   = blockIdx.x;
    const int b     = gid / (C / CPB);
    const int chunk = (gid % (C / CPB)) * CPB + (threadIdx.x >> 6);
    const int w     = threadIdx.x >> 6;
    const int lane  = threadIdx.x & 63;

    const long base = (long)(b * L + chunk * LC) * N4 + lane;

    // Prologue: DMA batch 0 (8 rows x 1 KB).
#pragma unroll
    for (int r = 0; r < SD; ++r)
        lds_dma16(x4 + base + (long)r * N4, &st[w][r][0]);

    floatx4 last = nan4();
    int f0 = LC, f1 = LC, f2 = LC, f3 = LC;

    constexpr int NB = LC / SD;                  // 4 batches
#pragma unroll
    for (int bk = 0; bk < NB; ++bk) {
        // Wait for this batch's 8 DMAs (oldest outstanding VMEM ops).
        // bk>0: 16 (or 8) NT stores from the previous batch were issued
        // AFTER those DMAs -> counted wait leaves them in flight.
        if (bk == 0) {
            asm volatile("s_waitcnt vmcnt(0)" ::: "memory");
        } else if constexpr (HASMASK) {
            asm volatile("s_waitcnt vmcnt(16)" ::: "memory");
        } else {
            asm volatile("s_waitcnt vmcnt(8)" ::: "memory");
        }

        // LDS -> registers.
        floatx4 v[SD];
#pragma unroll
        for (int r = 0; r < SD; ++r) v[r] = st[w][r][lane];

        // LDS slot WAR: reads must complete before re-issuing DMA into them.
        asm volatile("s_waitcnt lgkmcnt(0)" ::: "memory");
        __builtin_amdgcn_sched_barrier(0);

        if (bk + 1 < NB) {
#pragma unroll
            for (int r = 0; r < SD; ++r)
                lds_dma16(x4 + base + (long)((bk + 1) * SD + r) * N4,
                          &st[w][r][0]);
        }

        // Prefix + NT stores for this batch.
#pragma unroll
        for (int i = 0; i < SD; ++i) {
            const int row = bk * SD + i;
            const floatx4 val = v[i];
            const bool ox = (val.x == val.x);
            const bool oy = (val.y == val.y);
            const bool oz = (val.z == val.z);
            const bool ow = (val.w == val.w);
            if (ox && f0 == LC) f0 = row;        // cndmask, no branch
            if (oy && f1 == LC) f1 = row;
            if (oz && f2 == LC) f2 = row;
            if (ow && f3 == LC) f3 = row;
            upd(last, val);
            floatx4 o;
            o.x = (last.x == last.x) ? last.x : 0.0f;
            o.y = (last.y == last.y) ? last.y : 0.0f;
            o.z = (last.z == last.z) ? last.z : 0.0f;
            o.w = (last.w == last.w) ? last.w : 0.0f;
            __builtin_nontemporal_store(o, out4 + base + (long)row * N4);
            if constexpr (HASMASK) {
                floatx4 m = {ox ? 1.0f : 0.0f, oy ? 1.0f : 0.0f,
                             oz ? 1.0f : 0.0f, ow ? 1.0f : 0.0f};
                __builtin_nontemporal_store(m, m4 + base + (long)row * N4);
            }
        }
    }

    tail4[(long)(b * C + chunk) * N4 + lane] = last;
    fo[(long)(b * C + chunk) * 64 + lane] =
        (unsigned)f0 | ((unsigned)f1 << 8) | ((unsigned)f2 << 16) |
        ((unsigned)f3 << 24);
}

// ---------------- Pass 1 (register fallback, small ws) -------------------
template <int LC>
__global__ __launch_bounds__(256) void k_prefix_reg(const floatx4* __restrict__ x4,
                                                    floatx4* __restrict__ out4,
                                                    floatx4* __restrict__ m4,
                                                    floatx4* __restrict__ tail4,
                                                    unsigned int* __restrict__ fo) {
    constexpr int C = L / LC;
    const int gid   = blockIdx.x;
    const int b     = gid / (C / CPB);
    const int chunk = (gid % (C / CPB)) * CPB + (threadIdx.x >> 6);
    const int lane  = threadIdx.x & 63;

    const long base = (long)(b * L + chunk * LC) * N4 + lane;
    floatx4 last = nan4();
    int f0 = LC, f1 = LC, f2 = LC, f3 = LC;

    for (int g = 0; g < LC; g += 8) {
        floatx4 v[8];
#pragma unroll
        for (int i = 0; i < 8; ++i) v[i] = x4[base + (long)(g + i) * N4];
#pragma unroll
        for (int i = 0; i < 8; ++i) {
            const floatx4 val = v[i];
            const bool ox = (val.x == val.x);
            const bool oy = (val.y == val.y);
            const bool oz = (val.z == val.z);
            const bool ow = (val.w == val.w);
            if (ox && f0 == LC) f0 = g + i;
            if (oy && f1 == LC) f1 = g + i;
            if (oz && f2 == LC) f2 = g + i;
            if (ow && f3 == LC) f3 = g + i;
            upd(last, val);
            floatx4 o;
            o.x = (last.x == last.x) ? last.x : 0.0f;
            o.y = (last.y == last.y) ? last.y : 0.0f;
            o.z = (last.z == last.z) ? last.z : 0.0f;
            o.w = (last.w == last.w) ? last.w : 0.0f;
            __builtin_nontemporal_store(o, out4 + base + (long)(g + i) * N4);
            if (m4) {
                floatx4 m = {ox ? 1.0f : 0.0f, oy ? 1.0f : 0.0f,
                             oz ? 1.0f : 0.0f, ow ? 1.0f : 0.0f};
                __builtin_nontemporal_store(m, m4 + base + (long)(g + i) * N4);
            }
        }
    }
    tail4[(long)(b * C + chunk) * N4 + lane] = last;
    fo[(long)(b * C + chunk) * 64 + lane] =
        (unsigned)f0 | ((unsigned)f1 << 8) | ((unsigned)f2 << 16) |
        ((unsigned)f3 << 24);
}

// ---------------- Pass 2: tail scan + patch (unchanged from R5) ----------
template <int LC>
__global__ __launch_bounds__(64) void k_scan_patch(const floatx4* __restrict__ tail4,
                                                   const unsigned int* __restrict__ fo,
                                                   float* __restrict__ out) {
    constexpr int C = L / LC;
    constexpr int G = (C < 16) ? C : 16;
    const int b    = blockIdx.x;              // grid = B
    const int lane = threadIdx.x;             // one wave

    const floatx4*      t  = tail4 + (long)b * C * N4 + lane;
    const unsigned int* fp = fo    + (long)b * C * 64 + lane;

    floatx4 carry = nan4();
    for (int g = 0; g < C; g += G) {
        floatx4      tv[G];
        unsigned int fv[G];
#pragma unroll
        for (int j = 0; j < G; ++j) {
            tv[j] = t[(long)(g + j) * N4];
            fv[j] = fp[(long)(g + j) * 64];
        }
#pragma unroll
        for (int j = 0; j < G; ++j) {
            const int chunk = g + j;
            const unsigned fw = fv[j];
            const int f0 = fw & 255, f1 = (fw >> 8) & 255;
            const int f2 = (fw >> 16) & 255, f3 = fw >> 24;
            const bool c0 = (carry.x == carry.x);
            const bool c1 = (carry.y == carry.y);
            const bool c2 = (carry.z == carry.z);
            const bool c3 = (carry.w == carry.w);
            int pm = 0;
            if (c0) pm = max(pm, f0);
            if (c1) pm = max(pm, f1);
            if (c2) pm = max(pm, f2);
            if (c3) pm = max(pm, f3);
            if (pm > 0) {
                float* op = out + (long)(b * L + chunk * LC) * N + lane * 4;
                for (int i = 0; i < pm; ++i) {
                    if (c0 && i < f0) op[(long)i * N + 0] = carry.x;
                    if (c1 && i < f1) op[(long)i * N + 1] = carry.y;
                    if (c2 && i < f2) op[(long)i * N + 2] = carry.z;
                    if (c3 && i < f3) op[(long)i * N + 3] = carry.w;
                }
            }
            upd(carry, tv[j]);
        }
    }
}

extern "C" void kernel_launch(void* const* d_in, const int* in_sizes, int n_in,
                              void* d_out, int out_size, void* d_ws, size_t ws_size,
                              hipStream_t stream) {
    const float* x = (const float*)d_in[0];
    const long n_total = (long)B * L * N;  // 33,554,432

    float* out = (float*)d_out;
    float* mask_out = ((long)out_size >= 2 * n_total) ? out + n_total : nullptr;

    auto need = [](int C) { return (size_t)B * C * N * 5; };  // tails + fo

    if (ws_size >= need(L / LCD)) {
        // DMA path: LC=32 (C=128), 1024 blocks = 4 blocks/CU, 32 KB LDS each.
        constexpr int C = L / LCD;
        floatx4*      tail = (floatx4*)d_ws;
        unsigned int* fo   = (unsigned int*)((char*)d_ws + (size_t)B * C * N * 4);
        if (mask_out) {
            k_prefix_dma<true><<<B * C / CPB, 256, 0, stream>>>(
                (const floatx4*)x, (floatx4*)out, (floatx4*)mask_out, tail, fo);
        } else {
            k_prefix_dma<false><<<B * C / CPB, 256, 0, stream>>>(
                (const floatx4*)x, (floatx4*)out, nullptr, tail, fo);
        }
        k_scan_patch<LCD><<<B, 64, 0, stream>>>(tail, fo, out);
    } else if (ws_size >= need(L / 128)) {
        constexpr int LC = 128, C = L / LC;
        floatx4*      tail = (floatx4*)d_ws;
        unsigned int* fo   = (unsigned int*)((char*)d_ws + (size_t)B * C * N * 4);
        k_prefix_reg<LC><<<B * C / CPB, 256, 0, stream>>>(
            (const floatx4*)x, (floatx4*)out, (floatx4*)mask_out, tail, fo);
        k_scan_patch<LC><<<B, 64, 0, stream>>>(tail, fo, out);
    } else {
        constexpr int LC = 1024, C = L / LC;
        floatx4*      tail = (floatx4*)d_ws;
        unsigned int* fo   = (unsigned int*)((char*)d_ws + (size_t)B * C * N * 4);
        k_prefix_reg<LC><<<B * C / CPB, 256, 0, stream>>>(
            (const floatx4*)x, (floatx4*)out, (floatx4*)mask_out, tail, fo);
        k_scan_patch<LC><<<B, 64, 0, stream>>>(tail, fo, out);
    }
}